// Round 5
// baseline (71.285 us; speedup 1.0000x reference)
//
#include <hip/hip_runtime.h>

#define NPTS 4096
#define TOT  (2 * 8 * NPTS)   // 65536 rows

typedef __attribute__((ext_vector_type(8)))  short          bf16x8;
typedef __attribute__((ext_vector_type(8)))  unsigned short u16x8;
typedef __attribute__((ext_vector_type(16))) float          f32x16;

__device__ __forceinline__ unsigned short bf16_rne(float f) {
    unsigned u = __float_as_uint(f);
    u += 0x7FFFu + ((u >> 16) & 1u);
    return (unsigned short)(u >> 16);
}
__device__ __forceinline__ float bf16_f(unsigned short s) {
    return __uint_as_float(((unsigned)s) << 16);
}

// s(i,j) = ah.bh(3) + al.bh(3) + ah.bl(3) + 1*hh + 1*hl   (11 K-slots of 16)
// A slots: [ah0,ah1,ah2, al0,al1,al2, ah0,ah1 | ah2, 1, 1, 0,0,0,0,0]
// B slots: [bh0,bh1,bh2, bh0,bh1,bh2, bl0,bl1 | bl2, hh, hl, 0,0,0,0,0]
// 32x32x16 operand layout: lane l -> point (32u + (l&31)), k-slots 8*(l>>5)..+7.
// C/D map: col=lane&31, row=(reg&3)+8*(reg>>2)+4*(lane>>5). All HW-verified.
// R22 lesson: 1 wave/SIMD exposes ~10us of latency -> need TLP.
// R23 lesson: full-j blocks cost 4x conversion + serial staging -> keep jq split.
// R24: R21 geometry rebalanced for 4 waves/SIMD: 1024 blocks = 16 clouds x
//      16 iblk(256 rows) x 4 jq; 2 i-tiles/wave; no p0/p1 pipeline (TLP hides
//      MFMA latency); epilogue buf aliased onto sB; __launch_bounds__(256,4)
//      forces <=128 VGPR (m69 quantum: >128 caps at 2 waves/SIMD).

// ---------------- pass 0: MFMA chamfer core ----------------
// smaxp layout: [(dirb*16+iblk)*4+jq][256 rows]  (1 MB, every slot written)
__global__ __launch_bounds__(256, 4) void chamfer_mfma(
    const float* __restrict__ x, const float* __restrict__ y,
    float* __restrict__ smaxp, float* __restrict__ out)
{
    __shared__ __align__(16) char smem[33792];        // sB (32KB) U buf
    unsigned short* sB = (unsigned short*)smem;
    float (*buf)[64][33] = (float (*)[64][33])smem;   // aliased after barrier

    const int bid  = blockIdx.x;
    const int dirb = bid >> 6;        // 0..15 (A-cloud id)
    const int sub  = bid & 63;
    const int iblk = sub >> 2;        // 0..15 (256-row i-slab)
    const int jq   = sub & 3;         // 0..3  (1024-point j-quarter)

    const int tid = threadIdx.x;
    const int w   = tid >> 6;         // wave 0..3
    const int l   = tid & 63;
    const int g   = l >> 5;           // k-half
    const int pos = l & 31;           // row/col within tile

    if (bid == 0 && tid == 0) *out = 0.f;   // stream-ordered before reduce

    const float* Araw = (dirb < 8) ? x + (size_t)dirb * NPTS * 3
                                   : y + (size_t)(dirb - 8) * NPTS * 3;
    const int bcid = dirb ^ 8;
    const float* Braw = (bcid < 8) ? x + (size_t)bcid * NPTS * 3
                                   : y + (size_t)(bcid - 8) * NPTS * 3;

    // ---- convert this block's B quarter (1024 points) into LDS ----
    // byte layout: u*1024 + ppos*16 (+512 hi), u = 0..31
    #pragma unroll
    for (int k = 0; k < 4; ++k) {
        int p = k * 256 + tid;                       // 0..1023 local
        const float* src = Braw + (size_t)(jq * 1024 + p) * 3;
        float c0 = src[0], c1 = src[1], c2 = src[2];
        float h  = -0.5f * (c0 * c0 + c1 * c1 + c2 * c2);
        unsigned short h0 = bf16_rne(c0), h1 = bf16_rne(c1), h2 = bf16_rne(c2);
        unsigned short l0 = bf16_rne(c0 - bf16_f(h0));
        unsigned short l1 = bf16_rne(c1 - bf16_f(h1));
        unsigned short l2 = bf16_rne(c2 - bf16_f(h2));
        unsigned short hh = bf16_rne(h);
        unsigned short hl = bf16_rne(h - bf16_f(hh));
        u16x8 blo, bhi;
        blo[0]=h0; blo[1]=h1; blo[2]=h2; blo[3]=h0; blo[4]=h1; blo[5]=h2; blo[6]=l0; blo[7]=l1;
        bhi[0]=l2; bhi[1]=hh; bhi[2]=hl; bhi[3]=0; bhi[4]=0; bhi[5]=0; bhi[6]=0; bhi[7]=0;
        int u = p >> 5, ppos = p & 31;
        char* dst = (char*)sB + (size_t)u * 1024 + (size_t)ppos * 16;
        *(u16x8*)dst         = blo;
        *(u16x8*)(dst + 512) = bhi;
    }

    // ---- A fragments: 2 i-tiles per wave (verified recipe) ----
    const int it0 = iblk * 8 + w * 2;
    bf16x8 afr[2];
    #pragma unroll
    for (int t = 0; t < 2; ++t) {
        const float* ap = Araw + (size_t)((it0 + t) * 32 + pos) * 3;
        float c0 = ap[0], c1 = ap[1], c2 = ap[2];
        unsigned short h0 = bf16_rne(c0), h1 = bf16_rne(c1), h2 = bf16_rne(c2);
        unsigned short l0 = bf16_rne(c0 - bf16_f(h0));
        unsigned short l1 = bf16_rne(c1 - bf16_f(h1));
        unsigned short l2 = bf16_rne(c2 - bf16_f(h2));
        const short ONE = (short)0x3F80;
        bf16x8 alo, ahi;
        alo[0]=(short)h0; alo[1]=(short)h1; alo[2]=(short)h2; alo[3]=(short)l0;
        alo[4]=(short)l1; alo[5]=(short)l2; alo[6]=(short)h0; alo[7]=(short)h1;
        ahi[0]=(short)h2; ahi[1]=ONE; ahi[2]=ONE; ahi[3]=0;
        ahi[4]=0; ahi[5]=0; ahi[6]=0; ahi[7]=0;
        #pragma unroll
        for (int e = 0; e < 8; ++e) afr[t][e] = g ? ahi[e] : alo[e];
    }

    __syncthreads();   // LDS B tile ready

    f32x16 zc;
    #pragma unroll
    for (int r = 0; r < 16; ++r) zc[r] = 0.f;

    f32x16 run[2];
    #pragma unroll
    for (int t = 0; t < 2; ++t)
        #pragma unroll
        for (int r = 0; r < 16; ++r) run[t][r] = -3.0e38f;

    const char* Bq = (const char*)sB + (size_t)g * 512 + (size_t)pos * 16;

    // direct fold, no pipeline regs: 4 waves/SIMD hide MFMA latency
#define JPAIR(T, B0, B1)                                                        \
    {                                                                           \
        f32x16 d0 = __builtin_amdgcn_mfma_f32_32x32x16_bf16(afr[T], B0, zc, 0, 0, 0); \
        f32x16 d1 = __builtin_amdgcn_mfma_f32_32x32x16_bf16(afr[T], B1, zc, 0, 0, 0); \
        _Pragma("unroll")                                                       \
        for (int r = 0; r < 16; ++r)                                            \
            run[T][r] = fmaxf(fmaxf(d0[r], d1[r]), run[T][r]);                  \
    }

    #pragma unroll 1
    for (int j = 0; j < 32; j += 4) {
        const char* Bn = Bq + (size_t)j * 1024;
        bf16x8 cb0 = *(const bf16x8*)(Bn);
        bf16x8 cb1 = *(const bf16x8*)(Bn + 1024);
        bf16x8 cb2 = *(const bf16x8*)(Bn + 2048);
        bf16x8 cb3 = *(const bf16x8*)(Bn + 3072);
        JPAIR(0, cb0, cb1)
        JPAIR(1, cb0, cb1)
        JPAIR(0, cb2, cb3)
        JPAIR(1, cb2, cb3)
    }
#undef JPAIR

    __syncthreads();   // all sB reads done -> safe to alias smem as buf

    // ---- epilogue: 2 i-tiles -> 64 rows per wave (verified C/D map) ----
    #pragma unroll
    for (int tl = 0; tl < 2; ++tl) {
        #pragma unroll
        for (int r = 0; r < 16; ++r) {
            int rowin = (r & 3) + 8 * (r >> 2) + 4 * g;
            buf[w][tl * 32 + rowin][pos] = run[tl][r];
        }
    }
    __syncthreads();

    float m = buf[w][l][0];
    #pragma unroll
    for (int k = 1; k < 32; ++k) m = fmaxf(m, buf[w][l][k]);

    const int slotbase = (((dirb * 16 + iblk) * 4 + jq) << 8);
    smaxp[slotbase + w * 64 + l] = m;
}

// ---------------- pass 1: combine jq slots, add h_a from raw, sum ----------
__global__ __launch_bounds__(256) void reduce_kernel(
    const float* __restrict__ smaxp,
    const float* __restrict__ x, const float* __restrict__ y,
    float* __restrict__ out)
{
    const int stride = 64 * 256;
    int tid = blockIdx.x * 256 + threadIdx.x;
    float s = 0.f;
    for (int k = tid; k < TOT; k += stride) {
        int cid = k >> 12, ri = k & 4095;
        int iblk = ri >> 8, rem = ri & 255;
        const float* base = smaxp + (((cid * 16 + iblk) * 4) << 8) + rem;
        float m = fmaxf(fmaxf(base[0], base[256]),
                        fmaxf(base[512], base[768]));
        const float* ap = (cid < 8) ? x + ((size_t)cid * NPTS + ri) * 3
                                    : y + ((size_t)(cid - 8) * NPTS + ri) * 3;
        float a0 = ap[0], a1 = ap[1], a2 = ap[2];
        s += m - 0.5f * (a0 * a0 + a1 * a1 + a2 * a2);
    }

    #pragma unroll
    for (int off = 32; off > 0; off >>= 1)
        s += __shfl_down(s, off);

    __shared__ float redb[4];
    const int lane = threadIdx.x & 63, wave = threadIdx.x >> 6;
    if (lane == 0) redb[wave] = s;
    __syncthreads();
    if (threadIdx.x == 0) {
        float t = redb[0] + redb[1] + redb[2] + redb[3];
        // min_d = -2*(smax + h_a); loss = 0.005 * sum / 32768
        atomicAdd(out, t * (-2.0f * 0.005f / 32768.f));
    }
}

extern "C" void kernel_launch(void* const* d_in, const int* in_sizes, int n_in,
                              void* d_out, int out_size, void* d_ws, size_t ws_size,
                              hipStream_t stream) {
    const float* x = (const float*)d_in[0];
    const float* y = (const float*)d_in[1];
    float* out = (float*)d_out;

    float* smaxp = (float*)d_ws;   // 1 MB, every slot written each launch

    chamfer_mfma<<<dim3(1024), dim3(256), 0, stream>>>(x, y, smaxp, out);
    reduce_kernel<<<dim3(64), dim3(256), 0, stream>>>(smaxp, x, y, out);
}

// Round 6
// 67.181 us; speedup vs baseline: 1.0611x; 1.0611x over previous
//
#include <hip/hip_runtime.h>

#define NPTS 4096
#define NB   8
#define TOT  (2 * NB * NPTS)   // 65536 rows (dir*batch*point)

typedef __attribute__((ext_vector_type(8)))  short          bf16x8;
typedef __attribute__((ext_vector_type(8)))  unsigned short u16x8;
typedef __attribute__((ext_vector_type(16))) float          f32x16;

__device__ __forceinline__ unsigned short bf16_rne(float f) {
    unsigned u = __float_as_uint(f);
    u += 0x7FFFu + ((u >> 16) & 1u);
    return (unsigned short)(u >> 16);
}
__device__ __forceinline__ float bf16_f(unsigned short s) {
    return __uint_as_float(((unsigned)s) << 16);
}

// s(i,j) = ah.bh(3) + al.bh(3) + ah.bl(3) + 1*hh + 1*hl   (11 K-slots of 16)
// A slots: [ah0,ah1,ah2, al0,al1,al2, ah0,ah1 | ah2, 1, 1, 0,0,0,0,0]
// B slots: [bh0,bh1,bh2, bh0,bh1,bh2, bl0,bl1 | bl2, hh, hl, 0,0,0,0,0]
// 32x32x16 operand layout: lane l -> point (32u + (l&31)), k-slots 8*(l>>5)..+7.
// C/D map: col=lane&31, row=(reg&3)+8*(reg>>2)+4*(lane>>5). All HW-verified.
// R25 = exact revert to R21 (verified best: 66.49us, absmax 0.0).
// Lessons banked: R22 (1 wave/SIMD, +10us) — loop needs >=2 waves/SIMD.
//                 R23 (full-j, 4x conversion + serial staging, +3.7us).
//                 R24 (forced 128 VGPR + no pipeline/prefetch, +4.8us).
// R21 structure is a local optimum; remaining dur_us is dominated by the
// harness's 256MiB workspace poison fill (~40us) + reset dispatches.

// ---------------- pass 0: MFMA chamfer core ----------------
// grid = 16 (dir,b) * 8 i-blocks * 4 j-quarters = 512 blocks of 256 thr.
// smaxp layout: [(dirb*8+iblk)*4+jq][512 rows]  (1 MB, every slot written)
__global__ __launch_bounds__(256, 2) void chamfer_mfma(
    const float* __restrict__ x, const float* __restrict__ y,
    float* __restrict__ smaxp, float* __restrict__ out)
{
    __shared__ unsigned short sB[16384];   // 32 KB: B-quarter fragments
    __shared__ float buf[4][64][33];       // 33792 B, per-wave regions

    const int bid  = blockIdx.x;
    const int dirb = bid >> 5;        // 0..15 (A-cloud id)
    const int sub  = bid & 31;
    const int iblk = sub >> 2;        // 0..7
    const int jq   = sub & 3;         // 0..3

    const int tid = threadIdx.x;
    const int w   = tid >> 6;         // wave 0..3
    const int l   = tid & 63;
    const int g   = l >> 5;           // k-half
    const int pos = l & 31;           // row/col within tile

    if (bid == 0 && tid == 0) *out = 0.f;   // stream-ordered before reduce

    const float* Araw = (dirb < 8) ? x + (size_t)dirb * NPTS * 3
                                   : y + (size_t)(dirb - 8) * NPTS * 3;
    const int bcid = dirb ^ 8;
    const float* Braw = (bcid < 8) ? x + (size_t)bcid * NPTS * 3
                                   : y + (size_t)(bcid - 8) * NPTS * 3;

    // ---- convert this block's B quarter (1024 points) into LDS ----
    // byte layout identical to old Bform quarter: u*1024 + pos*16 (+512 hi)
    #pragma unroll
    for (int k = 0; k < 4; ++k) {
        int p = tid + k * 256;                       // 0..1023 local
        const float* src = Braw + (size_t)(jq * 1024 + p) * 3;
        float c0 = src[0], c1 = src[1], c2 = src[2];
        float h  = -0.5f * (c0 * c0 + c1 * c1 + c2 * c2);
        unsigned short h0 = bf16_rne(c0), h1 = bf16_rne(c1), h2 = bf16_rne(c2);
        unsigned short l0 = bf16_rne(c0 - bf16_f(h0));
        unsigned short l1 = bf16_rne(c1 - bf16_f(h1));
        unsigned short l2 = bf16_rne(c2 - bf16_f(h2));
        unsigned short hh = bf16_rne(h);
        unsigned short hl = bf16_rne(h - bf16_f(hh));
        u16x8 blo, bhi;
        blo[0]=h0; blo[1]=h1; blo[2]=h2; blo[3]=h0; blo[4]=h1; blo[5]=h2; blo[6]=l0; blo[7]=l1;
        bhi[0]=l2; bhi[1]=hh; bhi[2]=hl; bhi[3]=0; bhi[4]=0; bhi[5]=0; bhi[6]=0; bhi[7]=0;
        int u = p >> 5, ppos = p & 31;
        char* dst = (char*)sB + (size_t)u * 1024 + (size_t)ppos * 16;
        *(u16x8*)dst         = blo;
        *(u16x8*)(dst + 512) = bhi;
    }

    // ---- A fragments in-register from raw floats (R11/R15-verified) ----
    const int it0 = iblk * 16 + w * 4;
    bf16x8 afr[4];
    #pragma unroll
    for (int t = 0; t < 4; ++t) {
        const float* ap = Araw + (size_t)((it0 + t) * 32 + pos) * 3;
        float c0 = ap[0], c1 = ap[1], c2 = ap[2];
        unsigned short h0 = bf16_rne(c0), h1 = bf16_rne(c1), h2 = bf16_rne(c2);
        unsigned short l0 = bf16_rne(c0 - bf16_f(h0));
        unsigned short l1 = bf16_rne(c1 - bf16_f(h1));
        unsigned short l2 = bf16_rne(c2 - bf16_f(h2));
        const short ONE = (short)0x3F80;
        bf16x8 alo, ahi;
        alo[0]=(short)h0; alo[1]=(short)h1; alo[2]=(short)h2; alo[3]=(short)l0;
        alo[4]=(short)l1; alo[5]=(short)l2; alo[6]=(short)h0; alo[7]=(short)h1;
        ahi[0]=(short)h2; ahi[1]=ONE; ahi[2]=ONE; ahi[3]=0;
        ahi[4]=0; ahi[5]=0; ahi[6]=0; ahi[7]=0;
        #pragma unroll
        for (int e = 0; e < 8; ++e) afr[t][e] = g ? ahi[e] : alo[e];
    }

    __syncthreads();   // LDS B tile ready

    f32x16 zc;
    #pragma unroll
    for (int r = 0; r < 16; ++r) zc[r] = 0.f;

    f32x16 run[4];
    #pragma unroll
    for (int t = 0; t < 4; ++t)
        #pragma unroll
        for (int r = 0; r < 16; ++r) run[t][r] = -3.0e38f;

    // pipeline registers: previous stage's MFMA results (dummy-initialized;
    // first consume folds -3e38 into run[3] — harmless, run starts at -3e38)
    f32x16 p0, p1;
    #pragma unroll
    for (int r = 0; r < 16; ++r) { p0[r] = -3.0e38f; p1[r] = -3.0e38f; }

    const char* Bq = (const char*)sB + (size_t)g * 512 + (size_t)pos * 16;

    bf16x8 cb0 = *(const bf16x8*)(Bq);
    bf16x8 cb1 = *(const bf16x8*)(Bq + 1024);
    bf16x8 cb2 = *(const bf16x8*)(Bq + 2048);
    bf16x8 cb3 = *(const bf16x8*)(Bq + 3072);

#define STAGE(T, B0, B1, RP)                                                    \
    {                                                                           \
        f32x16 d0 = __builtin_amdgcn_mfma_f32_32x32x16_bf16(afr[T], B0, zc, 0, 0, 0); \
        f32x16 d1 = __builtin_amdgcn_mfma_f32_32x32x16_bf16(afr[T], B1, zc, 0, 0, 0); \
        _Pragma("unroll")                                                       \
        for (int r = 0; r < 16; ++r)                                            \
            run[RP][r] = fmaxf(fmaxf(p0[r], p1[r]), run[RP][r]);                \
        p0 = d0; p1 = d1;                                                       \
    }

    #pragma unroll 1
    for (int j = 0; j < 32; j += 4) {
        bf16x8 nb0, nb1, nb2, nb3;
        if (j < 28) {                       // wave-uniform scalar branch
            const char* Bn = Bq + (size_t)(j + 4) * 1024;
            nb0 = *(const bf16x8*)(Bn);
            nb1 = *(const bf16x8*)(Bn + 1024);
            nb2 = *(const bf16x8*)(Bn + 2048);
            nb3 = *(const bf16x8*)(Bn + 3072);
        }
        STAGE(0, cb0, cb1, 3)
        STAGE(1, cb0, cb1, 0)
        STAGE(2, cb0, cb1, 1)
        STAGE(3, cb0, cb1, 2)
        STAGE(0, cb2, cb3, 3)
        STAGE(1, cb2, cb3, 0)
        STAGE(2, cb2, cb3, 1)
        STAGE(3, cb2, cb3, 2)
        if (j < 28) { cb0 = nb0; cb1 = nb1; cb2 = nb2; cb3 = nb3; }
    }
#undef STAGE

    // drain: last stage used afr[3]
    #pragma unroll
    for (int r = 0; r < 16; ++r)
        run[3][r] = fmaxf(fmaxf(p0[r], p1[r]), run[3][r]);

    // ---- epilogue, 2 phases of 2 i-tiles each (verified R9/R13/R15/R16) ----
    // per-(block,jq) partial row-max -> disjoint slot, plain store (no atomics)
    const int slotbase = (((dirb * 8 + iblk) * 4 + jq) << 9);
    #pragma unroll
    for (int ph = 0; ph < 2; ++ph) {
        if (ph) __syncthreads();   // phase-0 reads done before overwrite
        #pragma unroll
        for (int tl = 0; tl < 2; ++tl) {
            const int t = 2 * ph + tl;
            #pragma unroll
            for (int r = 0; r < 16; ++r) {
                int rowin = (r & 3) + 8 * (r >> 2) + 4 * g;   // verified C/D map
                buf[w][tl * 32 + rowin][pos] = run[t][r];
            }
        }
        __syncthreads();

        float m = buf[w][l][0];
        #pragma unroll
        for (int k = 1; k < 32; ++k) m = fmaxf(m, buf[w][l][k]);
        smaxp[slotbase + w * 128 + ph * 64 + l] = m;
    }
}

// ---------------- pass 1: combine jq slots, add h_a from raw, sum ----------
__global__ __launch_bounds__(256) void reduce_kernel(
    const float* __restrict__ smaxp,
    const float* __restrict__ x, const float* __restrict__ y,
    float* __restrict__ out)
{
    const int stride = 64 * 256;
    int tid = blockIdx.x * 256 + threadIdx.x;
    float s = 0.f;
    for (int k = tid; k < TOT; k += stride) {
        int cid = k >> 12, ri = k & 4095;
        int iblk = ri >> 9, rem = ri & 511;
        const float* base = smaxp + (((cid * 8 + iblk) * 4) << 9) + rem;
        float m = fmaxf(fmaxf(base[0], base[512]),
                        fmaxf(base[1024], base[1536]));
        const float* ap = (cid < 8) ? x + ((size_t)cid * NPTS + ri) * 3
                                    : y + ((size_t)(cid - 8) * NPTS + ri) * 3;
        float a0 = ap[0], a1 = ap[1], a2 = ap[2];
        s += m - 0.5f * (a0 * a0 + a1 * a1 + a2 * a2);
    }

    #pragma unroll
    for (int off = 32; off > 0; off >>= 1)
        s += __shfl_down(s, off);

    __shared__ float redb[4];
    const int lane = threadIdx.x & 63, wave = threadIdx.x >> 6;
    if (lane == 0) redb[wave] = s;
    __syncthreads();
    if (threadIdx.x == 0) {
        float t = redb[0] + redb[1] + redb[2] + redb[3];
        // min_d = -2*(smax + h_a); loss = 0.005 * sum / 32768
        atomicAdd(out, t * (-2.0f * 0.005f / 32768.f));
    }
}

extern "C" void kernel_launch(void* const* d_in, const int* in_sizes, int n_in,
                              void* d_out, int out_size, void* d_ws, size_t ws_size,
                              hipStream_t stream) {
    const float* x = (const float*)d_in[0];
    const float* y = (const float*)d_in[1];
    float* out = (float*)d_out;

    float* smaxp = (float*)d_ws;   // 1 MB, every slot written each launch

    chamfer_mfma<<<dim3(512), dim3(256), 0, stream>>>(x, y, smaxp, out);
    reduce_kernel<<<dim3(64), dim3(256), 0, stream>>>(smaxp, x, y, out);
}

// Round 9
// 66.169 us; speedup vs baseline: 1.0773x; 1.0153x over previous
//
#include <hip/hip_runtime.h>

#define NPTS 4096
#define NB   8
#define TOT  (2 * NB * NPTS)   // 65536 rows (dir*batch*point)

typedef __attribute__((ext_vector_type(8)))  short          bf16x8;
typedef __attribute__((ext_vector_type(8)))  unsigned short u16x8;
typedef __attribute__((ext_vector_type(16))) float          f32x16;

__device__ __forceinline__ unsigned short bf16_rne(float f) {
    unsigned u = __float_as_uint(f);
    u += 0x7FFFu + ((u >> 16) & 1u);
    return (unsigned short)(u >> 16);
}
__device__ __forceinline__ float bf16_f(unsigned short s) {
    return __uint_as_float(((unsigned)s) << 16);
}

// s(i,j) = ah.bh(3) + al.bh(3) + ah.bl(3) + 1*hh + 1*hl   (11 K-slots of 16)
// A slots: [ah0,ah1,ah2, al0,al1,al2, ah0,ah1 | ah2, 1, 1, 0,0,0,0,0]
// B slots: [bh0,bh1,bh2, bh0,bh1,bh2, bl0,bl1 | bl2, hh, hl, 0,0,0,0,0]
// 32x32x16 operand layout: lane l -> point (32u + (l&31)), k-slots 8*(l>>5)..+7.
// C/D map: col=lane&31, row=(reg&3)+8*(reg>>2)+4*(lane>>5). All HW-verified.
// R28 = exact revert to R25/R21 (verified best: 66.49 / 67.18 us, absmax 0.0).
// Session ledger: R22 1 wave/SIMD +10us; R23 full-j +3.7us; R24 forced-128VGPR
//   +4.8us; R26/R27 cooperative fusion = silent launch failure (out never
//   written; absmax == |ref|, bit-identical across both memory-ordering
//   variants -> hipLaunchCooperativeKernel incompatible with harness graph
//   capture / zero-slack co-residency). Two-kernel R21 structure stands.
// Remaining dur_us is dominated by the harness 256MiB workspace poison fill
// (~40us @ ~84% HBM peak) + dispatch/reset overhead; our two kernels are
// ~8us combined and latency-balanced at 2 blocks/CU.

// ---------------- pass 0: MFMA chamfer core ----------------
// grid = 16 (dir,b) * 8 i-blocks * 4 j-quarters = 512 blocks of 256 thr.
// smaxp layout: [(dirb*8+iblk)*4+jq][512 rows]  (1 MB, every slot written)
__global__ __launch_bounds__(256, 2) void chamfer_mfma(
    const float* __restrict__ x, const float* __restrict__ y,
    float* __restrict__ smaxp, float* __restrict__ out)
{
    __shared__ unsigned short sB[16384];   // 32 KB: B-quarter fragments
    __shared__ float buf[4][64][33];       // 33792 B, per-wave regions

    const int bid  = blockIdx.x;
    const int dirb = bid >> 5;        // 0..15 (A-cloud id)
    const int sub  = bid & 31;
    const int iblk = sub >> 2;        // 0..7
    const int jq   = sub & 3;         // 0..3

    const int tid = threadIdx.x;
    const int w   = tid >> 6;         // wave 0..3
    const int l   = tid & 63;
    const int g   = l >> 5;           // k-half
    const int pos = l & 31;           // row/col within tile

    if (bid == 0 && tid == 0) *out = 0.f;   // stream-ordered before reduce

    const float* Araw = (dirb < 8) ? x + (size_t)dirb * NPTS * 3
                                   : y + (size_t)(dirb - 8) * NPTS * 3;
    const int bcid = dirb ^ 8;
    const float* Braw = (bcid < 8) ? x + (size_t)bcid * NPTS * 3
                                   : y + (size_t)(bcid - 8) * NPTS * 3;

    // ---- convert this block's B quarter (1024 points) into LDS ----
    // byte layout identical to old Bform quarter: u*1024 + pos*16 (+512 hi)
    #pragma unroll
    for (int k = 0; k < 4; ++k) {
        int p = tid + k * 256;                       // 0..1023 local
        const float* src = Braw + (size_t)(jq * 1024 + p) * 3;
        float c0 = src[0], c1 = src[1], c2 = src[2];
        float h  = -0.5f * (c0 * c0 + c1 * c1 + c2 * c2);
        unsigned short h0 = bf16_rne(c0), h1 = bf16_rne(c1), h2 = bf16_rne(c2);
        unsigned short l0 = bf16_rne(c0 - bf16_f(h0));
        unsigned short l1 = bf16_rne(c1 - bf16_f(h1));
        unsigned short l2 = bf16_rne(c2 - bf16_f(h2));
        unsigned short hh = bf16_rne(h);
        unsigned short hl = bf16_rne(h - bf16_f(hh));
        u16x8 blo, bhi;
        blo[0]=h0; blo[1]=h1; blo[2]=h2; blo[3]=h0; blo[4]=h1; blo[5]=h2; blo[6]=l0; blo[7]=l1;
        bhi[0]=l2; bhi[1]=hh; bhi[2]=hl; bhi[3]=0; bhi[4]=0; bhi[5]=0; bhi[6]=0; bhi[7]=0;
        int u = p >> 5, ppos = p & 31;
        char* dst = (char*)sB + (size_t)u * 1024 + (size_t)ppos * 16;
        *(u16x8*)dst         = blo;
        *(u16x8*)(dst + 512) = bhi;
    }

    // ---- A fragments in-register from raw floats (R11/R15-verified) ----
    const int it0 = iblk * 16 + w * 4;
    bf16x8 afr[4];
    #pragma unroll
    for (int t = 0; t < 4; ++t) {
        const float* ap = Araw + (size_t)((it0 + t) * 32 + pos) * 3;
        float c0 = ap[0], c1 = ap[1], c2 = ap[2];
        unsigned short h0 = bf16_rne(c0), h1 = bf16_rne(c1), h2 = bf16_rne(c2);
        unsigned short l0 = bf16_rne(c0 - bf16_f(h0));
        unsigned short l1 = bf16_rne(c1 - bf16_f(h1));
        unsigned short l2 = bf16_rne(c2 - bf16_f(h2));
        const short ONE = (short)0x3F80;
        bf16x8 alo, ahi;
        alo[0]=(short)h0; alo[1]=(short)h1; alo[2]=(short)h2; alo[3]=(short)l0;
        alo[4]=(short)l1; alo[5]=(short)l2; alo[6]=(short)h0; alo[7]=(short)h1;
        ahi[0]=(short)h2; ahi[1]=ONE; ahi[2]=ONE; ahi[3]=0;
        ahi[4]=0; ahi[5]=0; ahi[6]=0; ahi[7]=0;
        #pragma unroll
        for (int e = 0; e < 8; ++e) afr[t][e] = g ? ahi[e] : alo[e];
    }

    __syncthreads();   // LDS B tile ready

    f32x16 zc;
    #pragma unroll
    for (int r = 0; r < 16; ++r) zc[r] = 0.f;

    f32x16 run[4];
    #pragma unroll
    for (int t = 0; t < 4; ++t)
        #pragma unroll
        for (int r = 0; r < 16; ++r) run[t][r] = -3.0e38f;

    // pipeline registers: previous stage's MFMA results (dummy-initialized;
    // first consume folds -3e38 into run[3] — harmless, run starts at -3e38)
    f32x16 p0, p1;
    #pragma unroll
    for (int r = 0; r < 16; ++r) { p0[r] = -3.0e38f; p1[r] = -3.0e38f; }

    const char* Bq = (const char*)sB + (size_t)g * 512 + (size_t)pos * 16;

    bf16x8 cb0 = *(const bf16x8*)(Bq);
    bf16x8 cb1 = *(const bf16x8*)(Bq + 1024);
    bf16x8 cb2 = *(const bf16x8*)(Bq + 2048);
    bf16x8 cb3 = *(const bf16x8*)(Bq + 3072);

#define STAGE(T, B0, B1, RP)                                                    \
    {                                                                           \
        f32x16 d0 = __builtin_amdgcn_mfma_f32_32x32x16_bf16(afr[T], B0, zc, 0, 0, 0); \
        f32x16 d1 = __builtin_amdgcn_mfma_f32_32x32x16_bf16(afr[T], B1, zc, 0, 0, 0); \
        _Pragma("unroll")                                                       \
        for (int r = 0; r < 16; ++r)                                            \
            run[RP][r] = fmaxf(fmaxf(p0[r], p1[r]), run[RP][r]);                \
        p0 = d0; p1 = d1;                                                       \
    }

    #pragma unroll 1
    for (int j = 0; j < 32; j += 4) {
        bf16x8 nb0, nb1, nb2, nb3;
        if (j < 28) {                       // wave-uniform scalar branch
            const char* Bn = Bq + (size_t)(j + 4) * 1024;
            nb0 = *(const bf16x8*)(Bn);
            nb1 = *(const bf16x8*)(Bn + 1024);
            nb2 = *(const bf16x8*)(Bn + 2048);
            nb3 = *(const bf16x8*)(Bn + 3072);
        }
        STAGE(0, cb0, cb1, 3)
        STAGE(1, cb0, cb1, 0)
        STAGE(2, cb0, cb1, 1)
        STAGE(3, cb0, cb1, 2)
        STAGE(0, cb2, cb3, 3)
        STAGE(1, cb2, cb3, 0)
        STAGE(2, cb2, cb3, 1)
        STAGE(3, cb2, cb3, 2)
        if (j < 28) { cb0 = nb0; cb1 = nb1; cb2 = nb2; cb3 = nb3; }
    }
#undef STAGE

    // drain: last stage used afr[3]
    #pragma unroll
    for (int r = 0; r < 16; ++r)
        run[3][r] = fmaxf(fmaxf(p0[r], p1[r]), run[3][r]);

    // ---- epilogue, 2 phases of 2 i-tiles each (verified R9/R13/R15/R16) ----
    // per-(block,jq) partial row-max -> disjoint slot, plain store (no atomics)
    const int slotbase = (((dirb * 8 + iblk) * 4 + jq) << 9);
    #pragma unroll
    for (int ph = 0; ph < 2; ++ph) {
        if (ph) __syncthreads();   // phase-0 reads done before overwrite
        #pragma unroll
        for (int tl = 0; tl < 2; ++tl) {
            const int t = 2 * ph + tl;
            #pragma unroll
            for (int r = 0; r < 16; ++r) {
                int rowin = (r & 3) + 8 * (r >> 2) + 4 * g;   // verified C/D map
                buf[w][tl * 32 + rowin][pos] = run[t][r];
            }
        }
        __syncthreads();

        float m = buf[w][l][0];
        #pragma unroll
        for (int k = 1; k < 32; ++k) m = fmaxf(m, buf[w][l][k]);
        smaxp[slotbase + w * 128 + ph * 64 + l] = m;
    }
}

// ---------------- pass 1: combine jq slots, add h_a from raw, sum ----------
__global__ __launch_bounds__(256) void reduce_kernel(
    const float* __restrict__ smaxp,
    const float* __restrict__ x, const float* __restrict__ y,
    float* __restrict__ out)
{
    const int stride = 64 * 256;
    int tid = blockIdx.x * 256 + threadIdx.x;
    float s = 0.f;
    for (int k = tid; k < TOT; k += stride) {
        int cid = k >> 12, ri = k & 4095;
        int iblk = ri >> 9, rem = ri & 511;
        const float* base = smaxp + (((cid * 8 + iblk) * 4) << 9) + rem;
        float m = fmaxf(fmaxf(base[0], base[512]),
                        fmaxf(base[1024], base[1536]));
        const float* ap = (cid < 8) ? x + ((size_t)cid * NPTS + ri) * 3
                                    : y + ((size_t)(cid - 8) * NPTS + ri) * 3;
        float a0 = ap[0], a1 = ap[1], a2 = ap[2];
        s += m - 0.5f * (a0 * a0 + a1 * a1 + a2 * a2);
    }

    #pragma unroll
    for (int off = 32; off > 0; off >>= 1)
        s += __shfl_down(s, off);

    __shared__ float redb[4];
    const int lane = threadIdx.x & 63, wave = threadIdx.x >> 6;
    if (lane == 0) redb[wave] = s;
    __syncthreads();
    if (threadIdx.x == 0) {
        float t = redb[0] + redb[1] + redb[2] + redb[3];
        // min_d = -2*(smax + h_a); loss = 0.005 * sum / 32768
        atomicAdd(out, t * (-2.0f * 0.005f / 32768.f));
    }
}

extern "C" void kernel_launch(void* const* d_in, const int* in_sizes, int n_in,
                              void* d_out, int out_size, void* d_ws, size_t ws_size,
                              hipStream_t stream) {
    const float* x = (const float*)d_in[0];
    const float* y = (const float*)d_in[1];
    float* out = (float*)d_out;

    float* smaxp = (float*)d_ws;   // 1 MB, every slot written each launch

    chamfer_mfma<<<dim3(512), dim3(256), 0, stream>>>(x, y, smaxp, out);
    reduce_kernel<<<dim3(64), dim3(256), 0, stream>>>(smaxp, x, y, out);
}